// Round 7
// baseline (97.479 us; speedup 1.0000x reference)
//
#include <hip/hip_runtime.h>

#define VOCAB 32000
#define EMB   1024
#define TPB_T 512
#define COLS  32                  // vocab cols per block (one 128B line per W row)
#define TILES (VOCAB / COLS)      // 1000
#define CH    512                 // emb rows per LDS chunk
#define NCHUNK (EMB / CH)         // 2

typedef float f32x4 __attribute__((ext_vector_type(4)));

// ---------------------------------------------------------------------------
// Kernel A: transpose W[EMB][VOCAB] -> WT[VOCAB][EMB] in d_ws.
// Per block: stage W[c0:c0+512, v0:v0+32] transposed + XOR-swizzled in 64KB
// LDS, then write 32 contiguous 2KB row segments of WT (block's total output
// = one contiguous 128KB region; page-friendly, sequential).
//   - W reads: nontemporal (read-once; keep L3 for WT)
//   - WT writes: plain (L3 write-allocate; stays dirty-resident across replays)
//   - LDS dword addr = col*512 + (row ^ ((col>>2)<<2)): staging writes exactly
//     2 lanes/bank (free), reads are conflict-free aligned ds_read_b128.
//   - chunk-1 loads issued before chunk-0 store phase (latency overlap).
// ---------------------------------------------------------------------------
__global__ __launch_bounds__(TPB_T) void tok_emb_transpose(
    const float* __restrict__ W, f32x4* __restrict__ WT4) {
    __shared__ float lds[COLS * CH];   // 64 KB

    const int v0  = blockIdx.x * COLS;
    const int tid = threadIdx.x;
    const int cg  = tid & 7;           // col group (4 floats); swizzle key
    const int rb  = tid >> 3;          // row base 0..63
    const int swz = cg << 2;           // row-XOR bits 2-4

    const float* wbase = W + (size_t)v0 + (size_t)(cg << 2);

    f32x4 r[8];
    auto issue = [&](int c0) {         // 8 x 128B full-line nt loads per thread
#pragma unroll
        for (int k = 0; k < 8; ++k)
            r[k] = __builtin_nontemporal_load(reinterpret_cast<const f32x4*>(
                wbase + (size_t)(c0 + rb + (k << 6)) * VOCAB));
    };
    auto commit = [&]() {              // regs -> LDS transpose scatter
#pragma unroll
        for (int k = 0; k < 8; ++k) {
            const int rs = (rb + (k << 6)) ^ swz;
#pragma unroll
            for (int j = 0; j < 4; ++j)
                lds[(((cg << 2) + j) << 9) + rs] = r[k][j];
        }
    };

    issue(0);
    commit();
    __syncthreads();
    for (int ch = 0; ch < NCHUNK; ++ch) {
        if (ch + 1 < NCHUNK) issue((ch + 1) * CH);   // overlap with stores
        const int c0 = ch * CH;
        // 32 cols * 128 f32x4 = 4096 stores; 8 iters/thread; 1KB/wave-inst.
        for (int j = tid; j < COLS * (CH / 4); j += TPB_T) {
            const int c = j >> 7;       // 0..31
            const int i = j & 127;      // f32x4 index within chunk
            const f32x4 v = *reinterpret_cast<const f32x4*>(
                lds + (c << 9) + ((i << 2) ^ (((c >> 2) & 7) << 2)));
            WT4[(size_t)(v0 + c) * (EMB / 4) + (c0 >> 2) + i] = v;  // plain: L3
        }
        __syncthreads();               // readers done
        if (ch + 1 < NCHUNK) {
            commit();
            __syncthreads();
        }
    }
}

// ---------------------------------------------------------------------------
// Kernel B: out[t, :] = WT[tokens[t], :]. One block per token; reads are 4KB
// contiguous L3 hits, writes sequential 4KB nt-stores (don't evict WT).
// ---------------------------------------------------------------------------
__global__ __launch_bounds__(256) void tok_emb_gather(
    const f32x4* __restrict__ WT4, const int* __restrict__ tokens,
    f32x4* __restrict__ out4) {
    const int t   = blockIdx.x;
    const int tok = tokens[t];
    const f32x4 v = WT4[(size_t)tok * (EMB / 4) + threadIdx.x];
    __builtin_nontemporal_store(v, &out4[(size_t)t * (EMB / 4) + threadIdx.x]);
}

// ---------------------------------------------------------------------------
// Fallback (ws too small for WT): direct column gather, correctness only.
// ---------------------------------------------------------------------------
__global__ __launch_bounds__(256) void tok_emb_direct(
    const float* __restrict__ W, const int* __restrict__ tokens,
    float* __restrict__ out) {
    const int t   = blockIdx.x;
    const int tok = tokens[t];
    for (int e = threadIdx.x; e < EMB; e += 256)
        out[(size_t)t * EMB + e] = W[(size_t)e * VOCAB + tok];
}

extern "C" void kernel_launch(void* const* d_in, const int* in_sizes, int n_in,
                              void* d_out, int out_size, void* d_ws, size_t ws_size,
                              hipStream_t stream) {
    const int*   tokens   = (const int*)d_in[0];   // [8*4096] int32
    const float* W        = (const float*)d_in[1]; // [1024][32000] f32
    f32x4*       out4     = (f32x4*)d_out;         // [32768][1024] f32
    const int    n_tokens = in_sizes[0];

    const size_t wt_bytes = (size_t)VOCAB * EMB * sizeof(float);
    if (ws_size >= wt_bytes) {
        f32x4* WT4 = (f32x4*)d_ws;
        tok_emb_transpose<<<TILES, TPB_T, 0, stream>>>(W, WT4);
        tok_emb_gather<<<n_tokens, 256, 0, stream>>>(WT4, tokens, (f32x4*)d_out);
    } else {
        tok_emb_direct<<<n_tokens, 256, 0, stream>>>(W, tokens, (float*)d_out);
    }
}

// Round 8
// 86.705 us; speedup vs baseline: 1.1243x; 1.1243x over previous
//
#include <hip/hip_runtime.h>

#define VOCAB 32000
#define EMB   1024
#define TPB   1024
#define COLS  256                 // vocab cols per tile: 1KB contiguous read per wave-inst
#define TILES (VOCAB / COLS)      // 125
#define RG    256                 // emb rows per block (4 row-groups cover EMB)
#define NRG   (EMB / RG)          // 4
#define CH    128                 // emb rows per LDS chunk (2 chunks per block)
#define CAP_T 512                 // per-tile bucket capacity (expected ~262, +15 sigma)

typedef float f32x4 __attribute__((ext_vector_type(4)));

// ---------------------------------------------------------------------------
// Pass 0: zero per-tile counters (d_ws is poisoned, not zeroed).
// ---------------------------------------------------------------------------
__global__ __launch_bounds__(256) void tok_emb_zero(int* __restrict__ cnt) {
    if (threadIdx.x < TILES) cnt[threadIdx.x] = 0;
}

// ---------------------------------------------------------------------------
// Pass 1: bucket tokens by 256-wide vocab tile.
// ---------------------------------------------------------------------------
__global__ __launch_bounds__(256) void tok_emb_bucket(
    const int* __restrict__ tokens, int* __restrict__ cnt,
    int* __restrict__ bucket, int n_tokens) {
    const int i4 = (blockIdx.x * 256 + threadIdx.x) * 4;
    if (i4 + 3 < n_tokens) {
        const int4 tk = *reinterpret_cast<const int4*>(&tokens[i4]);
        const int tv[4] = {tk.x, tk.y, tk.z, tk.w};
#pragma unroll
        for (int j = 0; j < 4; ++j) {
            const unsigned tile = (unsigned)tv[j] >> 8;
            if (tile < TILES) {
                const int p = atomicAdd(&cnt[tile], 1);
                if (p < CAP_T) bucket[tile * CAP_T + p] = ((i4 + j) << 8) | (tv[j] & 255);
            }
        }
    } else {
        for (int i = i4; i < n_tokens; ++i) {
            const unsigned tile = (unsigned)tokens[i] >> 8;
            if (tile < TILES) {
                const int p = atomicAdd(&cnt[tile], 1);
                if (p < CAP_T) bucket[tile * CAP_T + p] = (i << 8) | (tokens[i] & 255);
            }
        }
    }
}

// ---------------------------------------------------------------------------
// Pass 2: block = (tile: 256 vocab cols, rg: 256 emb rows). Two chunks of
// 128 rows each. Reads: each wave-instruction fetches ONE CONTIGUOUS 1KB
// row-chunk of W (64 lanes x f32x4) -- the read-granule experiment.
// LDS: col-major lds[c][r], dword addr = c*128 + (r ^ (((c>>2)&7)<<2));
// write-phase token reads are conflict-free b128 (each 32-lane group reads
// one full 512B column); staging writes are 8-way (negligible vs mem time).
// Chunk-1 loads issued before chunk-0's store phase (latency overlap).
// Block order rg-major: co-resident blocks cover whole W rows sequentially.
// ---------------------------------------------------------------------------
__global__ __launch_bounds__(TPB) void tok_emb_main(
    const float* __restrict__ W, const int* __restrict__ tokens,
    const int* __restrict__ cnt, const int* __restrict__ bucket,
    f32x4* __restrict__ out4, int n_tokens) {
    __shared__ float lds[COLS * CH];   // 128 KB
    __shared__ int   list[CAP_T];      // 2 KB
    __shared__ int   scnt;

    const int tile  = blockIdx.x % TILES;
    const int rg    = blockIdx.x / TILES;
    const int v0    = tile * COLS;
    const int rbase = rg * RG;
    const int tid   = threadIdx.x;

    const int g   = tid & 63;          // col group: cols 4g..4g+3
    const int r0  = tid >> 6;          // 0..15 (wave id)
    const int swz = (g & 7) << 2;      // row-XOR bits 2-4 (same for the 4 cols)

    const float* wbase = W + (size_t)v0 + (size_t)(g << 2);

    f32x4 rv[8];
    auto issue = [&](int c0) {         // 8 x (1KB-per-wave) loads per thread
#pragma unroll
        for (int k = 0; k < 8; ++k)
            rv[k] = *reinterpret_cast<const f32x4*>(
                wbase + (size_t)(rbase + c0 + r0 + (k << 4)) * VOCAB);
    };
    auto commit = [&]() {              // regs -> LDS transpose scatter
#pragma unroll
        for (int k = 0; k < 8; ++k) {
            const int rs = (r0 + (k << 4)) ^ swz;
#pragma unroll
            for (int j = 0; j < 4; ++j)
                lds[((g << 2) + j) * CH + rs] = rv[k][j];
        }
    };
    auto wphase = [&](int m, int ch) { // token row-segment stores (512B each)
        const int base4 = (rbase + ch * CH) >> 2;
        const int nst = m << 5;        // m tokens * 32 f32x4
        for (int j = tid; j < nst; j += TPB) {
            const int ent = list[j >> 5];
            const int i   = j & 31;
            const int t   = ent >> 8;
            const int c   = ent & 255;
            const f32x4 v = *reinterpret_cast<const f32x4*>(
                lds + c * CH + ((i << 2) ^ (((c >> 2) & 7) << 2)));
            __builtin_nontemporal_store(
                v, &out4[(size_t)t * (EMB / 4) + base4 + i]);
        }
    };

    const int m_total = (bucket != nullptr) ? cnt[tile] : CAP_T + 1;
    if (m_total <= CAP_T) {
        issue(0);                      // chunk-0 loads in flight during list load
        for (int j = tid; j < m_total; j += TPB)
            list[j] = bucket[tile * CAP_T + j];
        commit();
        __syncthreads();
        if (m_total == 0) return;
        issue(CH);                     // prefetch chunk 1 under chunk-0 stores
        wphase(m_total, 0);
        __syncthreads();
        commit();
        __syncthreads();
        wphase(m_total, 1);
    } else {
        // Structural backstop: segmented scan, CAP_T tokens per segment.
        for (int lo = 0; lo < n_tokens; lo += CAP_T) {
            const int hi = (lo + CAP_T < n_tokens) ? lo + CAP_T : n_tokens;
            __syncthreads();
            if (tid == 0) scnt = 0;
            __syncthreads();
            for (int i = lo + tid; i < hi; i += TPB) {
                const unsigned d = (unsigned)(tokens[i] - v0);
                if (d < COLS) {
                    const int p = atomicAdd(&scnt, 1);
                    list[p] = (i << 8) | (int)d;
                }
            }
            __syncthreads();
            const int m = scnt;        // block-uniform
            if (m) {
                issue(0);
                commit();
                __syncthreads();
                issue(CH);
                wphase(m, 0);
                __syncthreads();
                commit();
                __syncthreads();
                wphase(m, 1);
            }
        }
    }
}

extern "C" void kernel_launch(void* const* d_in, const int* in_sizes, int n_in,
                              void* d_out, int out_size, void* d_ws, size_t ws_size,
                              hipStream_t stream) {
    const int*   tokens   = (const int*)d_in[0];   // [8*4096] int32
    const float* W        = (const float*)d_in[1]; // [1024][32000] f32
    f32x4*       out4     = (f32x4*)d_out;         // [32768][1024] f32
    const int    n_tokens = in_sizes[0];

    const size_t need = (size_t)TILES * sizeof(int)
                      + (size_t)TILES * CAP_T * sizeof(int);
    if (ws_size >= need) {
        int* cnt    = (int*)d_ws;
        int* bucket = cnt + TILES;
        tok_emb_zero<<<1, 256, 0, stream>>>(cnt);
        const int quads = (n_tokens + 3) / 4;
        tok_emb_bucket<<<(quads + 255) / 256, 256, 0, stream>>>(
            tokens, cnt, bucket, n_tokens);
        tok_emb_main<<<TILES * NRG, TPB, 0, stream>>>(
            W, tokens, cnt, bucket, out4, n_tokens);
    } else {
        tok_emb_main<<<TILES * NRG, TPB, 0, stream>>>(
            W, tokens, nullptr, nullptr, out4, n_tokens);
    }
}

// Round 9
// 56.387 us; speedup vs baseline: 1.7288x; 1.5377x over previous
//
#include <hip/hip_runtime.h>

#define VOCAB 32000
#define EMB   1024
#define TPB   512
#define COLS  32                  // vocab cols per tile = one 128B line per W row
#define TILES (VOCAB / COLS)      // 1000
#define CH    512                 // emb rows per chunk -> 2KB contiguous nt-stores
#define NCHUNK (EMB / CH)         // 2
#define CAP   256                 // match-list capacity (expected ~33/tile)

typedef float f32x4 __attribute__((ext_vector_type(4)));

// ---------------------------------------------------------------------------
// Single dispatch. Block = one 32-col vocab tile:
//   1) issue chunk-0 W loads (8 x 128B full lines / thread, in flight)
//   2) scan all tokens (int4-vectorized, L2-resident) -> LDS match list
//      -- scan hides under the W-load latency
//   3) commit regs -> LDS transposed + XOR-swizzled
//      dword addr = col*512 + (row ^ ((col>>2)<<2))
//      staging writes: exactly 2 lanes/bank (free); token reads:
//      aligned conflict-free ds_read_b128 (swizzle only touches row bits 2-4)
//   4) per chunk: prefetch next chunk's W loads, then stream each matched
//      token's 2KB contiguous nt-store segment
// ---------------------------------------------------------------------------
__global__ __launch_bounds__(TPB) void tok_emb_fused(
    const float* __restrict__ W, const int* __restrict__ tokens,
    f32x4* __restrict__ out4, int n_tokens) {
    __shared__ float lds[COLS * CH];   // 64 KB
    __shared__ int   list[CAP];        // 1 KB
    __shared__ int   scnt;

    const int tile = blockIdx.x;
    const int v0   = tile * COLS;
    const int tid  = threadIdx.x;

    const int cg  = tid & 7;           // col group (4 floats); swizzle key
    const int rb  = tid >> 3;          // row base 0..63
    const int swz = cg << 2;           // row-XOR bits 2-4

    const float* wbase = W + (size_t)v0 + (size_t)(cg << 2);

    f32x4 r[8];
    auto issue = [&](int c0) {         // 8 x 128B full-line loads per thread
#pragma unroll
        for (int k = 0; k < 8; ++k)
            r[k] = *reinterpret_cast<const f32x4*>(
                wbase + (size_t)(c0 + rb + (k << 6)) * VOCAB);
    };
    auto commit = [&]() {              // regs -> LDS transpose scatter
#pragma unroll
        for (int k = 0; k < 8; ++k) {
            const int rs = (rb + (k << 6)) ^ swz;
#pragma unroll
            for (int j = 0; j < 4; ++j)
                lds[(((cg << 2) + j) << 9) + rs] = r[k][j];
        }
    };
    auto wphase = [&](int m, int ch) { // m tokens * 128 f32x4 (2KB each)
        const int base4 = ch * (CH / 4);
        const int nst = m << 7;
        for (int j = tid; j < nst; j += TPB) {
            const int ent = list[j >> 7];
            const int i   = j & 127;
            const int t   = ent >> 5;
            const int c   = ent & 31;
            const f32x4 v = *reinterpret_cast<const f32x4*>(
                lds + (c << 9) + ((i << 2) ^ ((c >> 2) << 2)));
            __builtin_nontemporal_store(
                v, &out4[(size_t)t * (EMB / 4) + base4 + i]);
        }
    };
    auto scan = [&](int lo, int hi) {  // match tokens in [lo,hi) to this tile
        const int nv = (hi - lo) >> 2;
        for (int q = tid; q < nv; q += TPB) {
            const int4 tk = *reinterpret_cast<const int4*>(&tokens[lo + (q << 2)]);
            const int tv[4] = {tk.x, tk.y, tk.z, tk.w};
#pragma unroll
            for (int j = 0; j < 4; ++j) {
                const unsigned d = (unsigned)(tv[j] - v0);
                if (d < COLS) {
                    const int p = atomicAdd(&scnt, 1);
                    if (p < CAP) list[p] = ((lo + (q << 2) + j) << 5) | (int)d;
                }
            }
        }
        for (int i = lo + (nv << 2) + tid; i < hi; i += TPB) {
            const unsigned d = (unsigned)(tokens[i] - v0);
            if (d < COLS) {
                const int p = atomicAdd(&scnt, 1);
                if (p < CAP) list[p] = (i << 5) | (int)d;
            }
        }
    };

    // ---- main flow
    if (tid == 0) scnt = 0;
    issue(0);                          // W loads in flight during the scan
    __syncthreads();                   // scnt=0 visible
    scan(0, n_tokens);                 // hides under W-load latency
    commit();                          // drains loads into LDS
    __syncthreads();                   // list + tile staged
    const int m_total = scnt;          // block-uniform

    if (m_total <= CAP) {
        if (m_total == 0) return;
        issue(CH);                     // prefetch chunk 1 under chunk-0 stores
        wphase(m_total, 0);
        __syncthreads();               // LDS readers done
        commit();
        __syncthreads();
        wphase(m_total, 1);
    } else {
        // Structural backstop (never taken for uniform-random tokens):
        // segmented rescan, CAP tokens per segment -> list can't overflow.
        for (int lo = 0; lo < n_tokens; lo += CAP) {
            const int hi = (lo + CAP < n_tokens) ? lo + CAP : n_tokens;
            __syncthreads();
            if (tid == 0) scnt = 0;
            __syncthreads();
            scan(lo, hi);
            __syncthreads();
            const int m = scnt;
            if (m) {
                issue(0);
                commit();
                __syncthreads();
                issue(CH);
                wphase(m, 0);
                __syncthreads();
                commit();
                __syncthreads();
                wphase(m, 1);
            }
        }
    }
}

extern "C" void kernel_launch(void* const* d_in, const int* in_sizes, int n_in,
                              void* d_out, int out_size, void* d_ws, size_t ws_size,
                              hipStream_t stream) {
    const int*   tokens   = (const int*)d_in[0];   // [8*4096] int32
    const float* W        = (const float*)d_in[1]; // [1024][32000] f32
    f32x4*       out4     = (f32x4*)d_out;         // [32768][1024] f32
    const int    n_tokens = in_sizes[0];

    tok_emb_fused<<<TILES, TPB, 0, stream>>>(W, tokens, out4, n_tokens);
}